// Round 7
// baseline (27134.775 us; speedup 1.0000x reference)
//
#include <hip/hip_runtime.h>
#include <hip/hip_bf16.h>
#include <math.h>

// TransformerBlock B=4 S=2048 H=16 dh=64 D=1024 FF=2048.
// ROUND 7: naive all-fp32 pipeline, FP32 OUTPUT (reference returns fp32).
// Inputs remain dtype-polymorphic via detect_k (fp32 vs bf16).
// Buffers: qkv fp32 in ws[0,100.6M) with in-place rope; V fp32 [100.6M,134.2M);
// att staged in d_out; x/h overlay dead qkv region. WS_NEED=135MB (< proven 151.8MB).

typedef __bf16 bf16_t;

#define B_  4
#define S_  2048
#define H_  16
#define DH_ 64
#define D_  1024
#define FF_ 2048
#define M_  (B_ * S_)   // 8192

__device__ __forceinline__ float ldx(const void* p, int i, int f) {
    return f ? ((const float*)p)[i] : (float)((const bf16_t*)p)[i];
}

// ---- detect input dtype from Q's bit patterns; flag[0]=1 iff fp32; flag[1]=1 ----
__global__ void detect_k(const unsigned short* q, int n, int* flag) {
    const int tid = threadIdx.x;           // single block of 256
    float cnt = 0.f;
    for (int i = tid; i < n; i += 256) {
        const int e = (q[i] >> 7) & 0xFF;  // bf16 exponent field
        if (e >= 134) cnt += 1.f;          // impossible for N(0,1) bf16
    }
    __shared__ float red[256];
    red[tid] = cnt;
    __syncthreads();
    for (int s = 128; s > 0; s >>= 1) {
        if (tid < s) red[tid] += red[tid + s];
        __syncthreads();
    }
    if (tid == 0) { flag[0] = (red[0] > 0.5f) ? 1 : 0; flag[1] = 1; }
}

// ---------------- rope tables ----------------
__global__ void rope_tables_k(float* __restrict__ ct, float* __restrict__ st,
                              float* __restrict__ sct) {
    const int s = blockIdx.x, i = threadIdx.x;   // grid S_, block 32
    const float inv_freq = powf(10000.f, -(float)i / 32.f);
    const float f = (float)s * inv_freq;
    ct[s * 32 + i] = cosf(f);
    st[s * 32 + i] = sinf(f);
    const float base = (2.f * (float)i + 25.6f) / 89.6f;
    const float pw = ((float)s - 1024.f) / 512.f;
    sct[s * 32 + i] = powf(base, pw);
}

// ------------- naive GEMM: C[M,N] = A @ Bw + bias (+silu) (+resid), fp32 out ----------
template <int ACT, bool RES>
__global__ __launch_bounds__(256)
void naive_gemm_k(const void* __restrict__ A, const int* __restrict__ fA,
                  const void* __restrict__ Bw, const int* __restrict__ fB,
                  const void* __restrict__ bias, const int* __restrict__ fbias,
                  const float* __restrict__ resid, float* __restrict__ C,
                  int M, int N, int K) {
    const int id = blockIdx.x * 256 + threadIdx.x;
    if (id >= M * N) return;
    const int fa = fA[0], fb = fB[0], fc = fbias[0];
    const int row = id / N, col = id % N;
    float acc = ldx(bias, col, fc);
    const int abase = row * K;
    for (int k = 0; k < K; ++k)
        acc += ldx(A, abase + k, fa) * ldx(Bw, k * N + col, fb);
    if constexpr (ACT == 1) acc = acc / (1.f + expf(-acc));
    if constexpr (RES) acc += resid[(size_t)row * N + col];
    C[(size_t)row * N + col] = acc;
}

// ------------- qkv post: in-place l2norm+scale+rope on q,k; v -> Vr -------------
__global__ __launch_bounds__(256)
void qkv_post_k(float* __restrict__ qkv,
                const void* __restrict__ qsc, const void* __restrict__ ksc,
                const int* __restrict__ flag,
                const float* __restrict__ ct, const float* __restrict__ st,
                const float* __restrict__ sct, float* __restrict__ Vr) {
    const int id = blockIdx.x * 256 + threadIdx.x;   // [0, M_*H_)
    if (id >= M_ * H_) return;
    const int f = flag[0];
    const int bs = id >> 4, h = id & 15;
    const int s = bs & (S_ - 1), b = bs >> 11;
    float* row = qkv + (size_t)bs * (3 * D_) + h * 192;
    const size_t vb = ((size_t)(b * H_ + h) * S_ + s) * DH_;

    float q[DH_];
    // ---- q ----
    float n2 = 0.f;
#pragma unroll
    for (int d = 0; d < DH_; ++d) { q[d] = row[d]; n2 += q[d] * q[d]; }
    float inv = 1.f / fmaxf(sqrtf(n2), 1e-12f);
#pragma unroll
    for (int d = 0; d < DH_; ++d) q[d] *= inv * ldx(qsc, d, f);
#pragma unroll
    for (int d = 0; d < 32; ++d) {
        const float c = ct[s * 32 + d], sn = st[s * 32 + d], sc = sct[s * 32 + d];
        const float a = q[d], bb = q[d + 32];
        q[d]      = (a * c - bb * sn) * sc;
        q[d + 32] = (bb * c + a * sn) * sc;
    }
#pragma unroll
    for (int d = 0; d < DH_; ++d) row[d] = q[d];
    // ---- k ----
    n2 = 0.f;
#pragma unroll
    for (int d = 0; d < DH_; ++d) { q[d] = row[64 + d]; n2 += q[d] * q[d]; }
    inv = 1.f / fmaxf(sqrtf(n2), 1e-12f);
#pragma unroll
    for (int d = 0; d < DH_; ++d) q[d] *= inv * ldx(ksc, d, f);
#pragma unroll
    for (int d = 0; d < 32; ++d) {
        const float c = ct[s * 32 + d], sn = st[s * 32 + d], isc = 1.f / sct[s * 32 + d];
        const float a = q[d], bb = q[d + 32];
        q[d]      = (a * c - bb * sn) * isc;
        q[d + 32] = (bb * c + a * sn) * isc;
    }
#pragma unroll
    for (int d = 0; d < DH_; ++d) row[64 + d] = q[d];
    // ---- v ----
#pragma unroll
    for (int d = 0; d < DH_; ++d) Vr[vb + d] = row[128 + d];
}

// ------------- naive attention: one thread per (b,h,sq), two-pass, fp32 -------------
__global__ __launch_bounds__(256)
void attn_naive_k(const float* __restrict__ qkv, const float* __restrict__ Vr,
                  float* __restrict__ att) {
    const int id = blockIdx.x * 256 + threadIdx.x;   // [0, B_*H_*S_)
    if (id >= B_ * H_ * S_) return;
    const int hb = id >> 11, sq = id & (S_ - 1);
    const int b = hb >> 4, h = hb & 15;

    float q[DH_];
    const float* qrow = qkv + (size_t)(b * S_ + sq) * (3 * D_) + h * 192;
#pragma unroll
    for (int d = 0; d < DH_; ++d) q[d] = qrow[d];
    const float* Vb = Vr + (size_t)hb * S_ * DH_;

    float mx = -1e30f;
    for (int j = 0; j < S_; ++j) {
        const float* kj = qkv + (size_t)(b * S_ + j) * (3 * D_) + h * 192 + 64;
        float dot = 0.f;
#pragma unroll
        for (int d = 0; d < DH_; ++d) dot += q[d] * kj[d];
        mx = fmaxf(mx, dot * 0.125f);
    }
    float o[DH_];
#pragma unroll
    for (int d = 0; d < DH_; ++d) o[d] = 0.f;
    float sum = 0.f;
    for (int j = 0; j < S_; ++j) {
        const float* kj = qkv + (size_t)(b * S_ + j) * (3 * D_) + h * 192 + 64;
        float dot = 0.f;
#pragma unroll
        for (int d = 0; d < DH_; ++d) dot += q[d] * kj[d];
        const float p = expf(fminf(dot * 0.125f - mx, 0.f));
        sum += p;
        const float* vj = Vb + (size_t)j * DH_;
#pragma unroll
        for (int d = 0; d < DH_; ++d) o[d] += p * vj[d];
    }
    const float isum = 1.f / fmaxf(sum, 1e-20f);
    float* orow = att + (size_t)(b * S_ + sq) * D_ + h * DH_;
#pragma unroll
    for (int d = 0; d < DH_; ++d) orow[d] = o[d] * isum;
}

// ------------- LayerNorm over D=1024, fp32 in/out -------------
__global__ __launch_bounds__(256)
void layernorm_k(const float* __restrict__ in, const void* __restrict__ g,
                 const void* __restrict__ be, const int* __restrict__ flag,
                 float* __restrict__ xo) {
    const int row = blockIdx.x, tid = threadIdx.x;
    const int lane = tid & 63, wave = tid >> 6;
    const int f = flag[0];
    const float* r = in + (size_t)row * D_;
    float v[4], s = 0.f, ss = 0.f;
#pragma unroll
    for (int i = 0; i < 4; ++i) {
        v[i] = r[tid + i * 256];
        s += v[i]; ss += v[i] * v[i];
    }
#pragma unroll
    for (int msk = 1; msk < 64; msk <<= 1) { s += __shfl_xor(s, msk); ss += __shfl_xor(ss, msk); }
    __shared__ float rs[4], rss[4];
    if (lane == 0) { rs[wave] = s; rss[wave] = ss; }
    __syncthreads();
    s = rs[0] + rs[1] + rs[2] + rs[3];
    ss = rss[0] + rss[1] + rss[2] + rss[3];
    const float mu = s * (1.f / (float)D_);
    const float var = fmaxf(ss * (1.f / (float)D_) - mu * mu, 0.f);
    const float inv = rsqrtf(var + 1e-5f);
    float* xr = xo + (size_t)row * D_;
#pragma unroll
    for (int i = 0; i < 4; ++i) {
        const int c = tid + i * 256;
        xr[c] = (v[i] - mu) * inv * ldx(g, c, f) + ldx(be, c, f);
    }
}

__global__ void host_marker_k(int code, float* __restrict__ out) {
    if (code != 0) out[0] = 1e10f * (float)(1 + code);
}

extern "C" void kernel_launch(void* const* d_in, const int* in_sizes, int n_in,
                              void* d_out, int out_size, void* d_ws, size_t ws_size,
                              hipStream_t stream) {
    (void)out_size;
    const void* Q    = d_in[0];
    const void* Wqkv = d_in[3];
    const void* bqkv = d_in[4];
    const void* qsc  = d_in[5];
    const void* ksc  = d_in[6];
    const void* ln_g = d_in[7];
    const void* ln_b = d_in[8];
    const void* W1   = d_in[9];
    const void* b1   = d_in[10];
    const void* W2   = d_in[11];
    const void* b2   = d_in[12];

    // ws layout (bytes): qkv fp32 [0,100663296) -> later xbuf [0,33554432) +
    // hbuf [33554432,100663296); Vr fp32 [100663296,134217728); rope+flag tail.
    constexpr size_t OFF_QKV  = 0;
    constexpr size_t OFF_X    = 0;
    constexpr size_t OFF_HB   = 33554432;
    constexpr size_t OFF_VR   = 100663296;
    constexpr size_t OFF_RC   = OFF_VR + 33554432;   // 134217728
    constexpr size_t OFF_RS   = OFF_RC + 262144;
    constexpr size_t OFF_RSC  = OFF_RS + 262144;
    constexpr size_t OFF_FLAG = OFF_RSC + 262144;    // 135004160
    constexpr size_t WS_NEED  = OFF_FLAG + 64;

    float* out = (float*)d_out;                      // FP32 output (and att scratch)
    char* ws = (char*)d_ws;
    float* qkv  = (float*)(ws + OFF_QKV);
    float* xbuf = (float*)(ws + OFF_X);
    float* hbuf = (float*)(ws + OFF_HB);
    float* Vr   = (float*)(ws + OFF_VR);
    float* rc   = (float*)(ws + OFF_RC);
    float* rsn  = (float*)(ws + OFF_RS);
    float* rsc  = (float*)(ws + OFF_RSC);
    int*   flag = (int*)(ws + OFF_FLAG);   // flag[0]=input dtype (1=fp32), flag[1]=1

    int err_stage = 0;
    (void)hipGetLastError();
    #define LCHK(stage) do { if (hipGetLastError() != hipSuccess && err_stage == 0) err_stage = (stage); } while (0)

    if (n_in != 13) err_stage = 90;
    else if (in_sizes[0] != 8388608 || in_sizes[3] != 3145728 || in_sizes[4] != 3072 ||
             in_sizes[5] != 64 || in_sizes[7] != 1024 || in_sizes[9] != 2097152 ||
             in_sizes[10] != 2048 || in_sizes[11] != 2097152 || in_sizes[12] != 1024)
        err_stage = 91;
    else if (ws_size < WS_NEED) err_stage = 92;
    if (err_stage != 0) {
        host_marker_k<<<1, 1, 0, stream>>>(err_stage, out);
        return;
    }

    detect_k<<<1, 256, 0, stream>>>((const unsigned short*)Q, 65536, flag);        LCHK(1);
    rope_tables_k<<<S_, 32, 0, stream>>>(rc, rsn, rsc);                            LCHK(2);
    // qkv = Q @ Wqkv + bqkv  (fp32)
    naive_gemm_k<0, false><<<(M_ * 3 * D_) / 256, 256, 0, stream>>>(
        Q, flag, Wqkv, flag, bqkv, flag, nullptr, qkv, M_, 3 * D_, D_);            LCHK(3);
    // in-place l2norm + scale + rope on q,k; v -> Vr
    qkv_post_k<<<(M_ * H_) / 256, 256, 0, stream>>>(
        qkv, qsc, ksc, flag, rc, rsn, rsc, Vr);                                    LCHK(4);
    // attention -> att staged in d_out (fp32)
    attn_naive_k<<<(B_ * H_ * S_) / 256, 256, 0, stream>>>(qkv, Vr, out);          LCHK(5);
    // LayerNorm(att) -> xbuf (qkv region now dead)
    layernorm_k<<<M_, 256, 0, stream>>>(out, ln_g, ln_b, flag, xbuf);              LCHK(6);
    // h = silu(x @ W1 + b1)   (fp32 ws inputs use flag[1]=1)
    naive_gemm_k<1, false><<<(M_ * FF_) / 256, 256, 0, stream>>>(
        xbuf, flag + 1, W1, flag, b1, flag, nullptr, hbuf, M_, FF_, D_);           LCHK(7);
    // out = x + h @ W2 + b2  (overwrites att scratch)
    naive_gemm_k<0, true><<<(M_ * D_) / 256, 256, 0, stream>>>(
        hbuf, flag + 1, W2, flag, b2, flag, xbuf, out, M_, D_, FF_);               LCHK(8);
    host_marker_k<<<1, 1, 0, stream>>>(err_stage, out);
    #undef LCHK
}